// Round 1
// baseline (421.968 us; speedup 1.0000x reference)
//
#include <hip/hip_runtime.h>
#include <cstdint>

// CrossAttentionFusion: seq_len=1 cross-attention => softmax==1 => attention is
// identity on V. Whole net collapses to:
//   W1 = w_o1 @ wv1 ; b1 = w_o1 @ bv1 + b_o1   (wv1 = w_qkv1[2d:3d,:])
//   z  = [x_u @ W1^T + b1 , x_m @ W2^T + b2]   [B, 2d]
//   out = gelu( LN(z; g,b) @ w_proj^T + b_proj )
// LN folded into proj epilogue: h = rstd*(z.Wp'^T - mu*S) + C,
//   Wp'[j,c] = g[c]*w_proj[j,c], S[j] = sum_c g[c]*w_proj[j,c],
//   C[j] = sum_c b[c]*w_proj[j,c] + b_proj[j].

#define DIM 1024
#define BROWS 16384

typedef __bf16 bf16x8 __attribute__((ext_vector_type(8)));
typedef float f32x4 __attribute__((ext_vector_type(4)));

__device__ __forceinline__ ushort f2bf(float f) {
    uint32_t u = __builtin_bit_cast(uint32_t, f);
    u = (u + 0x7fffu + ((u >> 16) & 1u)) >> 16;
    return (ushort)u;
}

// global -> LDS direct copy, 16B per lane. LDS dest must be wave-uniform base;
// HW writes lane i at base + i*16.
__device__ __forceinline__ void async_copy16(const void* gsrc, void* ldst) {
    __builtin_amdgcn_global_load_lds(
        (__attribute__((address_space(1))) void*)((uintptr_t)gsrc),
        (__attribute__((address_space(3))) void*)((uint32_t)(uintptr_t)ldst),
        16, 0, 0);
}

// ---------------- prep kernels ----------------

__global__ __launch_bounds__(256) void convert_x_kernel(
        const float4* __restrict__ xu, const float4* __restrict__ xm,
        ushort4* __restrict__ out, int n4) {
    int i = blockIdx.x * 256 + threadIdx.x;
    int stride = gridDim.x * 256;
    for (; i < 2 * n4; i += stride) {
        float4 v = (i < n4) ? xu[i] : xm[i - n4];
        ushort4 o;
        o.x = f2bf(v.x); o.y = f2bf(v.y); o.z = f2bf(v.z); o.w = f2bf(v.w);
        out[i] = o;
    }
}

__global__ __launch_bounds__(256) void convert_w_kernel(
        const float4* __restrict__ wo1, const float4* __restrict__ wo2,
        const float4* __restrict__ wproj, const float* __restrict__ lng,
        ushort4* __restrict__ wo12, ushort4* __restrict__ Wp) {
    const int NWO = (DIM * DIM) / 4;       // 262144 per matrix
    const int NWP = (DIM * 2 * DIM) / 4;   // 524288
    int i = blockIdx.x * 256 + threadIdx.x;
    int stride = gridDim.x * 256;
    for (; i < 2 * NWO + NWP; i += stride) {
        if (i < 2 * NWO) {
            float4 v = (i < NWO) ? wo1[i] : wo2[i - NWO];
            ushort4 o;
            o.x = f2bf(v.x); o.y = f2bf(v.y); o.z = f2bf(v.z); o.w = f2bf(v.w);
            wo12[i] = o;
        } else {
            int j = i - 2 * NWO;
            float4 v = wproj[j];
            int c = (j * 4) & (2 * DIM - 1);
            v.x *= lng[c]; v.y *= lng[c + 1]; v.z *= lng[c + 2]; v.w *= lng[c + 3];
            ushort4 o;
            o.x = f2bf(v.x); o.y = f2bf(v.y); o.z = f2bf(v.z); o.w = f2bf(v.w);
            Wp[j] = o;
        }
    }
}

// wvT12[z][k][m] = w_qkv_z[2d + m][k]  (bf16), z in {0,1}
__global__ __launch_bounds__(256) void transpose_wv_kernel(
        const float* __restrict__ wqkv1, const float* __restrict__ wqkv2,
        ushort* __restrict__ wvT12) {
    int i = blockIdx.x * 256 + threadIdx.x;
    if (i >= 2 * DIM * DIM) return;
    int z = i >> 20;
    int r = i & (DIM * DIM - 1);
    int k = r >> 10;
    int m = r & (DIM - 1);
    const float* src = z ? wqkv2 : wqkv1;
    wvT12[i] = f2bf(src[(2 * DIM + m) * DIM + k]);
}

// b12[z*D+j], S[j], C[j]
__global__ __launch_bounds__(256) void vecprep_kernel(
        const float* __restrict__ wo1, const float* __restrict__ bqkv1, const float* __restrict__ bo1,
        const float* __restrict__ wo2, const float* __restrict__ bqkv2, const float* __restrict__ bo2,
        const float* __restrict__ wproj, const float* __restrict__ lng,
        const float* __restrict__ lnb, const float* __restrict__ bproj,
        float* __restrict__ b12, float* __restrict__ Svec, float* __restrict__ Cvec) {
    int j = blockIdx.x, t = threadIdx.x;
    float s1 = 0.f, s2 = 0.f, sS = 0.f, sC = 0.f;
    for (int c = t; c < DIM; c += 256) {
        s1 += wo1[j * DIM + c] * bqkv1[2 * DIM + c];
        s2 += wo2[j * DIM + c] * bqkv2[2 * DIM + c];
    }
    for (int c = t; c < 2 * DIM; c += 256) {
        float w = wproj[j * 2 * DIM + c];
        sS += w * lng[c];
        sC += w * lnb[c];
    }
    for (int o = 32; o; o >>= 1) {
        s1 += __shfl_down(s1, o, 64);
        s2 += __shfl_down(s2, o, 64);
        sS += __shfl_down(sS, o, 64);
        sC += __shfl_down(sC, o, 64);
    }
    __shared__ float red[4][4];
    int wid = t >> 6;
    if ((t & 63) == 0) { red[wid][0] = s1; red[wid][1] = s2; red[wid][2] = sS; red[wid][3] = sC; }
    __syncthreads();
    if (t == 0) {
        s1 = red[0][0] + red[1][0] + red[2][0] + red[3][0];
        s2 = red[0][1] + red[1][1] + red[2][1] + red[3][1];
        sS = red[0][2] + red[1][2] + red[2][2] + red[3][2];
        sC = red[0][3] + red[1][3] + red[2][3] + red[3][3];
        b12[j]       = s1 + bo1[j];
        b12[DIM + j] = s2 + bo2[j];
        Svec[j] = sS;
        Cvec[j] = sC + bproj[j];
    }
}

// per-row mean / rstd of z [B, 2048] bf16
__global__ __launch_bounds__(256) void stats_kernel(
        const ushort* __restrict__ z, float* __restrict__ mu, float* __restrict__ rstd) {
    int row = blockIdx.x, t = threadIdx.x;
    const uint4* zr = (const uint4*)(z + (long)row * 2 * DIM);
    uint4 v = zr[t];  // 8 bf16
    uint32_t u[4] = {v.x, v.y, v.z, v.w};
    float s = 0.f, q = 0.f;
#pragma unroll
    for (int i = 0; i < 4; i++) {
        float a = __builtin_bit_cast(float, u[i] << 16);
        float b = __builtin_bit_cast(float, u[i] & 0xffff0000u);
        s += a + b;
        q += a * a + b * b;
    }
    for (int o = 32; o; o >>= 1) {
        s += __shfl_down(s, o, 64);
        q += __shfl_down(q, o, 64);
    }
    __shared__ float red[4][2];
    int wid = t >> 6;
    if ((t & 63) == 0) { red[wid][0] = s; red[wid][1] = q; }
    __syncthreads();
    if (t == 0) {
        s = red[0][0] + red[1][0] + red[2][0] + red[3][0];
        q = red[0][1] + red[1][1] + red[2][1] + red[3][1];
        float m = s * (1.f / 2048.f);
        float var = q * (1.f / 2048.f) - m * m;
        mu[row] = m;
        rstd[row] = rsqrtf(var + 1e-5f);
    }
}

// ---------------- core GEMM (NT: C[m][n] = sum_k A[m][k] * W[n][k]) ----------------
// MODE 0: C bf16, no bias (weight fuse)
// MODE 1: C bf16 = acc + bias[zb*DIM + col]   (z GEMM; C offset by zb*sCz, ldc=2048)
// MODE 2: C fp32 = gelu(rstd[row]*(acc - mu[row]*S[col]) + Cv[col])  (proj GEMM)
template <int BM, int BN, int MODE>
__global__ __launch_bounds__(256, 2) void gemm_bt(
        const ushort* __restrict__ Ag, const ushort* __restrict__ Wg,
        void* __restrict__ Cg, int K, int lda, int ldw, int ldc,
        long sAz, long sWz, long sCz,
        const float* __restrict__ bias,
        const float* __restrict__ Svec, const float* __restrict__ Cvec,
        const float* __restrict__ mu, const float* __restrict__ rstd) {
    constexpr int BK = 32;
    constexpr int MT = BM / 32;  // 16x16 tiles per wave (M)
    constexpr int NT = BN / 32;
    __shared__ __align__(16) ushort As[BM * BK];
    __shared__ __align__(16) ushort Bs[BN * BK];
    const int tid = threadIdx.x;
    const int wid = tid >> 6;
    const int lane = tid & 63;
    const int quad = lane >> 4;
    const int l16 = lane & 15;
    const int waveM = wid >> 1, waveN = wid & 1;
    const int zb = blockIdx.z;

    const ushort* A = Ag + zb * sAz + (long)blockIdx.x * BM * lda;
    const ushort* W = Wg + zb * sWz + (long)blockIdx.y * BN * ldw;

    f32x4 acc[MT][NT] = {};

    constexpr int nA = (BM * BK) / (256 * 8);  // 16B chunks per thread
    constexpr int nB = (BN * BK) / (256 * 8);

    for (int k0 = 0; k0 < K; k0 += BK) {
#pragma unroll
        for (int c = 0; c < nA; c++) {
            int idx = c * 256 + tid;
            const ushort* g = A + (long)(idx >> 2) * lda + k0 + (idx & 3) * 8;
            async_copy16(g, (char*)As + (c * 256 + wid * 64) * 16);
        }
#pragma unroll
        for (int c = 0; c < nB; c++) {
            int idx = c * 256 + tid;
            const ushort* g = W + (long)(idx >> 2) * ldw + k0 + (idx & 3) * 8;
            async_copy16(g, (char*)Bs + (c * 256 + wid * 64) * 16);
        }
        asm volatile("s_waitcnt vmcnt(0)" ::: "memory");
        __syncthreads();

        bf16x8 af[MT], bfg[NT];
#pragma unroll
        for (int im = 0; im < MT; im++)
            af[im] = *(const bf16x8*)(As + (waveM * (BM / 2) + im * 16 + l16) * BK + quad * 8);
#pragma unroll
        for (int in = 0; in < NT; in++)
            bfg[in] = *(const bf16x8*)(Bs + (waveN * (BN / 2) + in * 16 + l16) * BK + quad * 8);
#pragma unroll
        for (int im = 0; im < MT; im++)
#pragma unroll
            for (int in = 0; in < NT; in++)
                acc[im][in] = __builtin_amdgcn_mfma_f32_16x16x32_bf16(
                    af[im], bfg[in], acc[im][in], 0, 0, 0);
        __syncthreads();
    }

    // epilogue: C/D layout col=lane&15, row=quad*4+reg  [verified m89/m91]
    const int gRow0 = blockIdx.x * BM + waveM * (BM / 2) + quad * 4;
    const int gCol0 = blockIdx.y * BN + waveN * (BN / 2) + l16;
    if constexpr (MODE == 0 || MODE == 1) {
        ushort* C = (ushort*)Cg + zb * sCz;
#pragma unroll
        for (int im = 0; im < MT; im++) {
#pragma unroll
            for (int in = 0; in < NT; in++) {
                int col = gCol0 + in * 16;
                float badd = 0.f;
                if constexpr (MODE == 1) badd = bias[zb * DIM + col];
#pragma unroll
                for (int r = 0; r < 4; r++) {
                    int row = gRow0 + im * 16 + r;
                    C[(long)row * ldc + col] = f2bf(acc[im][in][r] + badd);
                }
            }
        }
    } else {
        float* O = (float*)Cg;
#pragma unroll
        for (int im = 0; im < MT; im++) {
#pragma unroll
            for (int r = 0; r < 4; r++) {
                int row = gRow0 + im * 16 + r;
                float m = mu[row], rs = rstd[row];
#pragma unroll
                for (int in = 0; in < NT; in++) {
                    int col = gCol0 + in * 16;
                    float h = rs * (acc[im][in][r] - m * Svec[col]) + Cvec[col];
                    O[(long)row * ldc + col] = 0.5f * h * (1.0f + erff(h * 0.7071067811865475f));
                }
            }
        }
    }
}

// ---------------- launch ----------------

extern "C" void kernel_launch(void* const* d_in, const int* in_sizes, int n_in,
                              void* d_out, int out_size, void* d_ws, size_t ws_size,
                              hipStream_t stream) {
    (void)in_sizes; (void)n_in; (void)out_size; (void)ws_size;
    const float* x_u   = (const float*)d_in[0];
    const float* x_m   = (const float*)d_in[1];
    const float* wqkv1 = (const float*)d_in[2];
    const float* bqkv1 = (const float*)d_in[3];
    const float* wo1   = (const float*)d_in[4];
    const float* bo1   = (const float*)d_in[5];
    const float* wqkv2 = (const float*)d_in[6];
    const float* bqkv2 = (const float*)d_in[7];
    const float* wo2   = (const float*)d_in[8];
    const float* bo2   = (const float*)d_in[9];
    const float* lng   = (const float*)d_in[10];
    const float* lnb   = (const float*)d_in[11];
    const float* wproj = (const float*)d_in[12];
    const float* bproj = (const float*)d_in[13];

    char* ws = (char*)d_ws;
    ushort* x_bf  = (ushort*)(ws + 0);          // [2][B][D] bf16: 67,108,864 B
    ushort* wo12  = (ushort*)(ws + 67108864);   // [2][D][D]: 4 MB
    ushort* wvT12 = (ushort*)(ws + 71303168);   // [2][D][D]: 4 MB
    ushort* W12   = (ushort*)(ws + 75497472);   // [2][D][D]: 4 MB
    ushort* Wp    = (ushort*)(ws + 79691776);   // [D][2D]: 4 MB
    ushort* zbuf  = (ushort*)(ws + 83886080);   // [B][2D]: 67,108,864 B
    float*  b12   = (float*)(ws + 150994944);   // [2][D]
    float*  Svec  = (float*)(ws + 151003136);   // [D]
    float*  Cvec  = (float*)(ws + 151007232);   // [D]
    float*  mu    = (float*)(ws + 151011328);   // [B]
    float*  rstd  = (float*)(ws + 151076864);   // [B]
    // total ws use: 151,142,400 B

    convert_x_kernel<<<8192, 256, 0, stream>>>(
        (const float4*)x_u, (const float4*)x_m, (ushort4*)x_bf, (BROWS * DIM) / 4);
    convert_w_kernel<<<2048, 256, 0, stream>>>(
        (const float4*)wo1, (const float4*)wo2, (const float4*)wproj, lng,
        (ushort4*)wo12, (ushort4*)Wp);
    transpose_wv_kernel<<<8192, 256, 0, stream>>>(wqkv1, wqkv2, wvT12);
    vecprep_kernel<<<1024, 256, 0, stream>>>(
        wo1, bqkv1, bo1, wo2, bqkv2, bo2, wproj, lng, lnb, bproj, b12, Svec, Cvec);

    // W12[z] = wo12[z] @ wvT12[z]^T   (1024x1024, K=1024)
    gemm_bt<64, 64, 0><<<dim3(16, 16, 2), 256, 0, stream>>>(
        wo12, wvT12, W12, DIM, DIM, DIM, DIM,
        (long)DIM * DIM, (long)DIM * DIM, (long)DIM * DIM,
        nullptr, nullptr, nullptr, nullptr, nullptr);

    // z[:, z*D:(z+1)*D] = x_bf[z] @ W12[z]^T + b12[z]
    gemm_bt<128, 128, 1><<<dim3(128, 8, 2), 256, 0, stream>>>(
        x_bf, W12, zbuf, DIM, DIM, DIM, 2 * DIM,
        (long)BROWS * DIM, (long)DIM * DIM, (long)DIM,
        b12, nullptr, nullptr, nullptr, nullptr);

    stats_kernel<<<BROWS, 256, 0, stream>>>(zbuf, mu, rstd);

    // out = gelu(rstd*(z @ Wp^T - mu*S) + C)
    gemm_bt<128, 128, 2><<<dim3(128, 8, 1), 256, 0, stream>>>(
        zbuf, Wp, d_out, 2 * DIM, 2 * DIM, 2 * DIM, DIM,
        0, 0, 0,
        nullptr, Svec, Cvec, mu, rstd);
}

// Round 2
// 404.232 us; speedup vs baseline: 1.0439x; 1.0439x over previous
//
#include <hip/hip_runtime.h>
#include <cstdint>

// CrossAttentionFusion: seq_len=1 cross-attention => softmax==1 => attention is
// identity on V. Whole net collapses to:
//   W1 = w_o1 @ wv1 ; b1 = w_o1 @ bv1 + b_o1   (wv1 = w_qkv1[2d:3d,:])
//   z  = [x_u @ W1^T + b1 , x_m @ W2^T + b2]   [B, 2d]
//   out = gelu( LN(z; g,b) @ w_proj^T + b_proj )
// LN folded into proj epilogue: h = rstd*(z.Wp'^T - mu*S) + C,
//   Wp'[j,c] = g[c]*w_proj[j,c], S[j] = sum_c g[c]*w_proj[j,c],
//   C[j] = sum_c b[c]*w_proj[j,c] + b_proj[j].
// R2: XOR-swizzled LDS layout in GEMM (kill 8-way bank conflicts), stats fused
// into z-GEMM epilogue via atomics, all prep merged into one kernel with a
// coalesced LDS-tiled transpose.

#define DIM 1024
#define BROWS 16384

typedef __bf16 bf16x8 __attribute__((ext_vector_type(8)));
typedef float f32x4 __attribute__((ext_vector_type(4)));

__device__ __forceinline__ ushort f2bf(float f) {
    uint32_t u = __builtin_bit_cast(uint32_t, f);
    u = (u + 0x7fffu + ((u >> 16) & 1u)) >> 16;
    return (ushort)u;
}

// global -> LDS direct copy, 16B per lane. LDS dest is wave-uniform base;
// HW writes lane i at base + i*16.
__device__ __forceinline__ void async_copy16(const void* gsrc, void* ldst) {
    __builtin_amdgcn_global_load_lds(
        (__attribute__((address_space(1))) void*)((uintptr_t)gsrc),
        (__attribute__((address_space(3))) void*)((uint32_t)(uintptr_t)ldst),
        16, 0, 0);
}

// ---------------- merged prep kernel ----------------
// block ranges:
//  [0, 8192)        : convert x_u,x_m -> bf16            (8M float4 items)
//  [8192, 9216)     : vecprep (j = b-8192)
//  [9216, 12288)    : convert wo1,wo2, Wp=g*wproj -> bf16 (1.5M float4 items)
//  [12288, 14336)   : LDS-tiled transpose wv -> wvT bf16  (2048 32x32 tiles)
//  [14336, 14368)   : zero sumbuf/sqbuf (32768 floats)

__global__ __launch_bounds__(256) void prep_kernel(
        const float* __restrict__ x_u, const float* __restrict__ x_m,
        const float* __restrict__ wqkv1, const float* __restrict__ bqkv1,
        const float* __restrict__ wo1, const float* __restrict__ bo1,
        const float* __restrict__ wqkv2, const float* __restrict__ bqkv2,
        const float* __restrict__ wo2, const float* __restrict__ bo2,
        const float* __restrict__ lng, const float* __restrict__ lnb,
        const float* __restrict__ wproj, const float* __restrict__ bproj,
        ushort* __restrict__ x_bf, ushort* __restrict__ wo12,
        ushort* __restrict__ wvT12, ushort* __restrict__ Wp,
        float* __restrict__ b12, float* __restrict__ Svec, float* __restrict__ Cvec,
        float* __restrict__ sums /* sumbuf+sqbuf contiguous, 32768 floats */) {
    const int b = blockIdx.x, t = threadIdx.x;
    __shared__ float red[4][4];
    __shared__ float tls[32][33];

    if (b < 8192) {
        // ---- convert x (both halves) ----
        const int n4 = (BROWS * DIM) / 4;  // 4M float4 per x
        int i = b * 256 + t;
        const int stride = 8192 * 256;
        const float4* xu4 = (const float4*)x_u;
        const float4* xm4 = (const float4*)x_m;
        ushort4* o4 = (ushort4*)x_bf;
#pragma unroll
        for (int it = 0; it < 4; it++, i += stride) {
            float4 v = (i < n4) ? xu4[i] : xm4[i - n4];
            ushort4 o;
            o.x = f2bf(v.x); o.y = f2bf(v.y); o.z = f2bf(v.z); o.w = f2bf(v.w);
            o4[i] = o;
        }
    } else if (b < 9216) {
        // ---- vecprep: b12[z*D+j], S[j], C[j] ----
        int j = b - 8192;
        float s1 = 0.f, s2 = 0.f, sS = 0.f, sC = 0.f;
        for (int c = t; c < DIM; c += 256) {
            s1 += wo1[j * DIM + c] * bqkv1[2 * DIM + c];
            s2 += wo2[j * DIM + c] * bqkv2[2 * DIM + c];
        }
        for (int c = t; c < 2 * DIM; c += 256) {
            float w = wproj[j * 2 * DIM + c];
            sS += w * lng[c];
            sC += w * lnb[c];
        }
        for (int o = 32; o; o >>= 1) {
            s1 += __shfl_down(s1, o, 64);
            s2 += __shfl_down(s2, o, 64);
            sS += __shfl_down(sS, o, 64);
            sC += __shfl_down(sC, o, 64);
        }
        int wid = t >> 6;
        if ((t & 63) == 0) { red[wid][0] = s1; red[wid][1] = s2; red[wid][2] = sS; red[wid][3] = sC; }
        __syncthreads();
        if (t == 0) {
            s1 = red[0][0] + red[1][0] + red[2][0] + red[3][0];
            s2 = red[0][1] + red[1][1] + red[2][1] + red[3][1];
            sS = red[0][2] + red[1][2] + red[2][2] + red[3][2];
            sC = red[0][3] + red[1][3] + red[2][3] + red[3][3];
            b12[j]       = s1 + bo1[j];
            b12[DIM + j] = s2 + bo2[j];
            Svec[j] = sS;
            Cvec[j] = sC + bproj[j];
        }
    } else if (b < 12288) {
        // ---- convert weights ----
        const int NWO = (DIM * DIM) / 4;
        const int NWP = (DIM * 2 * DIM) / 4;
        const int total = 2 * NWO + NWP;
        int i = (b - 9216) * 256 + t;
        const int stride = 3072 * 256;
        for (; i < total; i += stride) {
            if (i < 2 * NWO) {
                float4 v = (i < NWO) ? ((const float4*)wo1)[i] : ((const float4*)wo2)[i - NWO];
                ushort4 o;
                o.x = f2bf(v.x); o.y = f2bf(v.y); o.z = f2bf(v.z); o.w = f2bf(v.w);
                ((ushort4*)wo12)[i] = o;
            } else {
                int j = i - 2 * NWO;
                float4 v = ((const float4*)wproj)[j];
                int c = (j * 4) & (2 * DIM - 1);
                v.x *= lng[c]; v.y *= lng[c + 1]; v.z *= lng[c + 2]; v.w *= lng[c + 3];
                ushort4 o;
                o.x = f2bf(v.x); o.y = f2bf(v.y); o.z = f2bf(v.z); o.w = f2bf(v.w);
                ((ushort4*)Wp)[j] = o;
            }
        }
    } else if (b < 14336) {
        // ---- transpose wv -> wvT (bf16), 32x32 fp32 tiles via LDS ----
        int tile = b - 12288;
        int z = tile >> 10;
        int t2 = tile & 1023;
        int mt = t2 >> 5, kt = t2 & 31;
        const float* src = z ? wqkv2 : wqkv1;  // wv = src + 2*DIM*DIM rows offset
        int tr = t >> 3;            // 0..31
        int tc4 = (t & 7) * 4;      // 0..28 step 4
        const float* p = src + (long)(2 * DIM + mt * 32 + tr) * DIM + kt * 32 + tc4;
        float4 v = *(const float4*)p;
        tls[tr][tc4 + 0] = v.x; tls[tr][tc4 + 1] = v.y;
        tls[tr][tc4 + 2] = v.z; tls[tr][tc4 + 3] = v.w;
        __syncthreads();
        // dst[k][m] = wv[m][k] = tls[m_local][k_local]
        ushort4 o;
        o.x = f2bf(tls[tc4 + 0][tr]);
        o.y = f2bf(tls[tc4 + 1][tr]);
        o.z = f2bf(tls[tc4 + 2][tr]);
        o.w = f2bf(tls[tc4 + 3][tr]);
        *(ushort4*)(wvT12 + (long)z * DIM * DIM + (long)(kt * 32 + tr) * DIM + mt * 32 + tc4) = o;
    } else {
        // ---- zero sums ----
        int i = (b - 14336) * 256 + t;   // 8192 float4
        ((float4*)sums)[i] = float4{0.f, 0.f, 0.f, 0.f};
    }
}

// ---------------- core GEMM (NT: C[m][n] = sum_k A[m][k] * W[n][k]) ----------------
// LDS layout XOR-swizzled: 16B chunk (row r, kchunk q) lives at slot
//   r*4 + (q ^ ((r>>1)&3))  -> each quad's 16-lane ds_read_b128 covers all 8
// bank groups exactly twice (2-way = free, m136).
// MODE 0: C bf16, no bias (weight fuse)
// MODE 1: C bf16 = acc + bias[zb*DIM + col]; fused LN-stats atomics
// MODE 2: C fp32 = gelu(rstd*(acc - mu*S) + Cv), mu/rstd from sums buffers
template <int BM, int BN, int MODE>
__global__ __launch_bounds__(256, 2) void gemm_bt(
        const ushort* __restrict__ Ag, const ushort* __restrict__ Wg,
        void* __restrict__ Cg, int K, int lda, int ldw, int ldc,
        long sAz, long sWz, long sCz,
        const float* __restrict__ bias,
        const float* __restrict__ Svec, const float* __restrict__ Cvec,
        float* __restrict__ sumbuf, float* __restrict__ sqbuf) {
    constexpr int BK = 32;
    constexpr int MT = BM / 32;
    constexpr int NT = BN / 32;
    __shared__ __align__(16) ushort As[BM * BK];
    __shared__ __align__(16) ushort Bs[BN * BK];
    const int tid = threadIdx.x;
    const int wid = tid >> 6;
    const int lane = tid & 63;
    const int quad = lane >> 4;
    const int l16 = lane & 15;
    const int waveM = wid >> 1, waveN = wid & 1;
    const int zb = blockIdx.z;

    const ushort* A = Ag + zb * sAz + (long)blockIdx.x * BM * lda;
    const ushort* W = Wg + zb * sWz + (long)blockIdx.y * BN * ldw;

    f32x4 acc[MT][NT] = {};

    constexpr int nA = (BM * BK) / (256 * 8);
    constexpr int nB = (BN * BK) / (256 * 8);

    // per-lane read swizzle: slot offset (in 8-elem units) within a row group
    const int swz = (l16 >> 1) & 3;
    const int rdA = quad ^ swz;   // applies to both A and B fragment reads
    for (int k0 = 0; k0 < K; k0 += BK) {
#pragma unroll
        for (int c = 0; c < nA; c++) {
            int idx = c * 256 + tid;
            int r = idx >> 2;
            int q = (idx & 3) ^ ((r >> 1) & 3);
            const ushort* g = A + (long)r * lda + k0 + q * 8;
            async_copy16(g, (char*)As + (c * 256 + wid * 64) * 16);
        }
#pragma unroll
        for (int c = 0; c < nB; c++) {
            int idx = c * 256 + tid;
            int r = idx >> 2;
            int q = (idx & 3) ^ ((r >> 1) & 3);
            const ushort* g = W + (long)r * ldw + k0 + q * 8;
            async_copy16(g, (char*)Bs + (c * 256 + wid * 64) * 16);
        }
        asm volatile("s_waitcnt vmcnt(0)" ::: "memory");
        __syncthreads();

        bf16x8 af[MT], bfg[NT];
#pragma unroll
        for (int im = 0; im < MT; im++)
            af[im] = *(const bf16x8*)(As + (waveM * (BM / 2) + im * 16 + l16) * BK + rdA * 8);
#pragma unroll
        for (int in = 0; in < NT; in++)
            bfg[in] = *(const bf16x8*)(Bs + (waveN * (BN / 2) + in * 16 + l16) * BK + rdA * 8);
#pragma unroll
        for (int im = 0; im < MT; im++)
#pragma unroll
            for (int in = 0; in < NT; in++)
                acc[im][in] = __builtin_amdgcn_mfma_f32_16x16x32_bf16(
                    af[im], bfg[in], acc[im][in], 0, 0, 0);
        __syncthreads();
    }

    // epilogue: C/D layout col=lane&15, row=quad*4+reg  [verified m89/m91]
    const int gRow0 = blockIdx.x * BM + waveM * (BM / 2) + quad * 4;
    const int gCol0 = blockIdx.y * BN + waveN * (BN / 2) + l16;
    if constexpr (MODE == 0) {
        ushort* C = (ushort*)Cg + zb * sCz;
#pragma unroll
        for (int im = 0; im < MT; im++)
#pragma unroll
            for (int in = 0; in < NT; in++) {
                int col = gCol0 + in * 16;
#pragma unroll
                for (int r = 0; r < 4; r++) {
                    int row = gRow0 + im * 16 + r;
                    C[(long)row * ldc + col] = f2bf(acc[im][in][r]);
                }
            }
    } else if constexpr (MODE == 1) {
        ushort* C = (ushort*)Cg + zb * sCz;
        float rs[MT][4] = {};
        float rq[MT][4] = {};
#pragma unroll
        for (int im = 0; im < MT; im++)
#pragma unroll
            for (int in = 0; in < NT; in++) {
                int col = gCol0 + in * 16;
                float badd = bias[zb * DIM + col];
#pragma unroll
                for (int r = 0; r < 4; r++) {
                    int row = gRow0 + im * 16 + r;
                    float val = acc[im][in][r] + badd;
                    C[(long)row * ldc + col] = f2bf(val);
                    rs[im][r] += val;
                    rq[im][r] += val * val;
                }
            }
        // reduce across the 16 lanes (l16) sharing each row, then atomics
#pragma unroll
        for (int im = 0; im < MT; im++)
#pragma unroll
            for (int r = 0; r < 4; r++) {
                float s = rs[im][r], q = rq[im][r];
#pragma unroll
                for (int o = 1; o < 16; o <<= 1) {
                    s += __shfl_xor(s, o, 64);
                    q += __shfl_xor(q, o, 64);
                }
                if (l16 == 0) {
                    int row = gRow0 + im * 16 + r;
                    atomicAdd(&sumbuf[row], s);
                    atomicAdd(&sqbuf[row], q);
                }
            }
    } else {
        float* O = (float*)Cg;
#pragma unroll
        for (int im = 0; im < MT; im++)
#pragma unroll
            for (int r = 0; r < 4; r++) {
                int row = gRow0 + im * 16 + r;
                float sv = sumbuf[row], qv = sqbuf[row];
                float m = sv * (1.f / 2048.f);
                float var = qv * (1.f / 2048.f) - m * m;
                float rstd = rsqrtf(var + 1e-5f);
#pragma unroll
                for (int in = 0; in < NT; in++) {
                    int col = gCol0 + in * 16;
                    float h = rstd * (acc[im][in][r] - m * Svec[col]) + Cvec[col];
                    O[(long)row * ldc + col] = 0.5f * h * (1.0f + erff(h * 0.7071067811865475f));
                }
            }
    }
}

// ---------------- launch ----------------

extern "C" void kernel_launch(void* const* d_in, const int* in_sizes, int n_in,
                              void* d_out, int out_size, void* d_ws, size_t ws_size,
                              hipStream_t stream) {
    (void)in_sizes; (void)n_in; (void)out_size; (void)ws_size;
    const float* x_u   = (const float*)d_in[0];
    const float* x_m   = (const float*)d_in[1];
    const float* wqkv1 = (const float*)d_in[2];
    const float* bqkv1 = (const float*)d_in[3];
    const float* wo1   = (const float*)d_in[4];
    const float* bo1   = (const float*)d_in[5];
    const float* wqkv2 = (const float*)d_in[6];
    const float* bqkv2 = (const float*)d_in[7];
    const float* wo2   = (const float*)d_in[8];
    const float* bo2   = (const float*)d_in[9];
    const float* lng   = (const float*)d_in[10];
    const float* lnb   = (const float*)d_in[11];
    const float* wproj = (const float*)d_in[12];
    const float* bproj = (const float*)d_in[13];

    char* ws = (char*)d_ws;
    ushort* x_bf  = (ushort*)(ws + 0);          // [2][B][D] bf16: 67,108,864 B
    ushort* wo12  = (ushort*)(ws + 67108864);   // [2][D][D]: 4 MB
    ushort* wvT12 = (ushort*)(ws + 71303168);   // [2][D][D]: 4 MB
    ushort* W12   = (ushort*)(ws + 75497472);   // [2][D][D]: 4 MB
    ushort* Wp    = (ushort*)(ws + 79691776);   // [D][2D]: 4 MB
    ushort* zbuf  = (ushort*)(ws + 83886080);   // [B][2D]: 67,108,864 B
    float*  b12   = (float*)(ws + 150994944);   // [2][D]
    float*  Svec  = (float*)(ws + 151003136);   // [D]
    float*  Cvec  = (float*)(ws + 151007232);   // [D]
    float*  sumbuf= (float*)(ws + 151011328);   // [B] row sums
    float*  sqbuf = (float*)(ws + 151076864);   // [B] row sumsq
    // total ws use: 151,142,400 B

    prep_kernel<<<14368, 256, 0, stream>>>(
        x_u, x_m, wqkv1, bqkv1, wo1, bo1, wqkv2, bqkv2, wo2, bo2,
        lng, lnb, wproj, bproj,
        x_bf, wo12, wvT12, Wp, b12, Svec, Cvec, sumbuf);

    // W12[z] = wo12[z] @ wvT12[z]^T   (1024x1024, K=1024)
    gemm_bt<64, 64, 0><<<dim3(16, 16, 2), 256, 0, stream>>>(
        wo12, wvT12, W12, DIM, DIM, DIM, DIM,
        (long)DIM * DIM, (long)DIM * DIM, (long)DIM * DIM,
        nullptr, nullptr, nullptr, nullptr, nullptr);

    // z[:, z*D:(z+1)*D] = x_bf[z] @ W12[z]^T + b12[z]  (+ fused LN stats)
    gemm_bt<128, 128, 1><<<dim3(128, 8, 2), 256, 0, stream>>>(
        x_bf, W12, zbuf, DIM, DIM, DIM, 2 * DIM,
        (long)BROWS * DIM, (long)DIM * DIM, (long)DIM,
        b12, nullptr, nullptr, sumbuf, sqbuf);

    // out = gelu(rstd*(z @ Wp^T - mu*S) + C)
    gemm_bt<128, 128, 2><<<dim3(128, 8, 1), 256, 0, stream>>>(
        zbuf, Wp, d_out, 2 * DIM, 2 * DIM, 2 * DIM, DIM,
        0, 0, 0,
        nullptr, Svec, Cvec, sumbuf, sqbuf);
}